// Round 5
// baseline (15.753 us; speedup 1.0000x reference)
//
#include <hip/hip_runtime.h>

// SurfEval: NURBS surface evaluation (B=4, 1024x1024 grid, 4x4 basis window).
// R4: software-pipelined 2-row blocks.
//  - 2048 blocks x 256 threads; block i handles rows bu = 2i, 2i+1 (same b,
//    consecutive u -> ctrl windows overlap -> L1/L2 hits).
//  - Stage-1 ctrl window for row r+1 is prefetched into REGISTERS before the
//    barrier of row r, hiding global-load latency under row r's stage 2.
//  - tu double-buffered in LDS (each buffer written once per block).
//  - v-mapping v = tid + 256k (consecutive lanes -> consecutive v): LDS reads
//    are ~11-distinct-entry broadcasts, conflict-free (fastest across R0-R3).
//  - vspan/Nv hoisted: loaded once, reused for both rows.
//  - nontemporal dwordx3 stores (streaming output, skip L2 write-allocate).
//  - perspective divide via v_rcp_f32 (absmax 7.8e-3 << 5.9e-2 threshold).

#define OUT_U 1024
#define OUT_V 1024
#define MCTRL 128
#define NCTRL 128
#define ROWS 2

typedef float vfloat3 __attribute__((ext_vector_type(3), aligned(4)));

__device__ __forceinline__ void fma4(float4& acc, float w, const float4& a) {
    acc.x = fmaf(w, a.x, acc.x);
    acc.y = fmaf(w, a.y, acc.y);
    acc.z = fmaf(w, a.z, acc.z);
    acc.w = fmaf(w, a.w, acc.w);
}

__global__ __launch_bounds__(256) void surf_eval_kernel(
    const float4* __restrict__ ctrl,   // (B,M,N)
    const float4* __restrict__ Nu,     // (OUT_U)
    const float4* __restrict__ Nv,     // (OUT_V)
    const int*    __restrict__ uspan,  // (OUT_U)
    const int*    __restrict__ vspan,  // (OUT_V)
    float*        __restrict__ out)    // (B,OUT_U,OUT_V,3)
{
    __shared__ float4 tu[ROWS][NCTRL];

    const int tid = threadIdx.x;
    const int bu0 = blockIdx.x * ROWS;

    // Hoisted row-invariant stage-2 operands (same v-mapping for both rows).
    int    vs[4];
    float4 nv[4];
#pragma unroll
    for (int k = 0; k < 4; ++k) {
        const int v = tid + k * 256;
        vs[k] = vspan[v];
        nv[k] = Nv[v];
    }

    // Prologue: load row 0's ctrl window into registers.
    float4 a0, a1, a2, a3, nu;
    if (tid < NCTRL) {
        const int bu = bu0;
        const int b  = bu >> 10;
        const int u  = bu & 1023;
        const int us = uspan[u];
        nu = Nu[u];
        const float4* row = ctrl + ((size_t)(b * MCTRL + (us - 3)) * NCTRL) + tid;
        a0 = row[0];
        a1 = row[NCTRL];
        a2 = row[2 * NCTRL];
        a3 = row[3 * NCTRL];
    }

#pragma unroll
    for (int r = 0; r < ROWS; ++r) {
        const int bu = bu0 + r;

        if (tid < NCTRL) {
            // u-contraction for row r (consumes a0..a3, nu).
            float4 acc;
            acc.x = nu.x * a0.x; acc.y = nu.x * a0.y;
            acc.z = nu.x * a0.z; acc.w = nu.x * a0.w;
            fma4(acc, nu.y, a1);
            fma4(acc, nu.z, a2);
            fma4(acc, nu.w, a3);
            tu[r][tid] = acc;

            // Prefetch row r+1's ctrl window (latency hides under stage 2).
            if (r + 1 < ROWS) {
                const int bun = bu0 + r + 1;
                const int bn  = bun >> 10;
                const int un  = bun & 1023;
                const int usn = uspan[un];
                nu = Nu[un];
                const float4* rown = ctrl + ((size_t)(bn * MCTRL + (usn - 3)) * NCTRL) + tid;
                a0 = rown[0];
                a1 = rown[NCTRL];
                a2 = rown[2 * NCTRL];
                a3 = rown[3 * NCTRL];
            }
        }
        __syncthreads();

        // Stage 2 for row r: 4 v-points per thread, broadcast LDS reads.
        const size_t outrow = (size_t)bu * OUT_V;
#pragma unroll
        for (int k = 0; k < 4; ++k) {
            const int v = tid + k * 256;

            const float4 t0 = tu[r][vs[k] - 3];
            const float4 t1 = tu[r][vs[k] - 2];
            const float4 t2 = tu[r][vs[k] - 1];
            const float4 t3 = tu[r][vs[k]];

            float4 acc;
            acc.x = nv[k].x * t0.x; acc.y = nv[k].x * t0.y;
            acc.z = nv[k].x * t0.z; acc.w = nv[k].x * t0.w;
            fma4(acc, nv[k].y, t1);
            fma4(acc, nv[k].z, t2);
            fma4(acc, nv[k].w, t3);

            const float inv = __builtin_amdgcn_rcpf(acc.w);
            vfloat3 res;
            res.x = acc.x * inv;
            res.y = acc.y * inv;
            res.z = acc.z * inv;
            __builtin_nontemporal_store(res, (vfloat3*)(out + (outrow + (size_t)v) * 3));
        }
        // No trailing barrier: next iteration writes tu[r+1] (distinct buffer),
        // and all LDS reads of tu[r] complete before each wave's next barrier
        // (lgkmcnt(0) precedes s_barrier).
    }
}

extern "C" void kernel_launch(void* const* d_in, const int* in_sizes, int n_in,
                              void* d_out, int out_size, void* d_ws, size_t ws_size,
                              hipStream_t stream) {
    const float4* ctrl  = (const float4*)d_in[0];
    const float4* Nu    = (const float4*)d_in[1];
    const float4* Nv    = (const float4*)d_in[2];
    const int*    uspan = (const int*)d_in[3];
    const int*    vspan = (const int*)d_in[4];
    float*        out   = (float*)d_out;

    const int nblocks = (4 * OUT_U) / ROWS; // 2048 blocks, 2 rows each
    surf_eval_kernel<<<nblocks, 256, 0, stream>>>(ctrl, Nu, Nv, uspan, vspan, out);
}